// Round 8
// baseline (3064.310 us; speedup 1.0000x reference)
//
#include <hip/hip_runtime.h>

#define N_NODES 50000
#define N_EDGES 1600000
#define F 11
#define FEAT 27   // 2F + 1 + ED
#define NLAYERS 4
#define NGRAPH 500
#define NVALS 14        // 11 msg_h + 3 msg_x
#define PRESTRIDE 24    // padded pre-table row: m[0..12), x[12..24)
#define NBLK 196        // ceil(N_NODES/256)
#define CHUNK_NODES 25  // nodes per edge-kernel block
#define NCHUNK 2000     // N_NODES / CHUNK_NODES

__device__ __forceinline__ float siluf(float v) { return v * (1.0f / (1.0f + __expf(-v))); }
__device__ __forceinline__ float sigmf(float v) { return 1.0f / (1.0f + __expf(-v)); }

// ---------- one-time edge sort by dst (counting sort) ----------
__global__ __launch_bounds__(256) void hist_kernel(const int* __restrict__ dst,
                                                   int* __restrict__ deg) {
    int e = blockIdx.x * 256 + threadIdx.x;
    if (e < N_EDGES) atomicAdd(&deg[dst[e]], 1);
}

__global__ __launch_bounds__(256) void scan1_kernel(const int* __restrict__ deg,
                                                    int* __restrict__ part,
                                                    int* __restrict__ bsum) {
    int t = threadIdx.x;
    int i = blockIdx.x * 256 + t;
    int v = (i < N_NODES) ? deg[i] : 0;
    int lane = t & 63, wid = t >> 6;
    int s = v;
    #pragma unroll
    for (int off = 1; off < 64; off <<= 1) {
        int u = __shfl_up(s, off);
        if (lane >= off) s += u;
    }
    __shared__ int wsum[4];
    if (lane == 63) wsum[wid] = s;
    __syncthreads();
    int wpre = 0;
    #pragma unroll
    for (int w = 0; w < 4; ++w) if (w < wid) wpre += wsum[w];
    if (i < N_NODES) part[i] = s + wpre - v;
    if (t == 255) bsum[blockIdx.x] = s + wpre;
}

__global__ __launch_bounds__(256) void scan2_kernel(int* __restrict__ bsum) {
    int t = threadIdx.x;
    int v = (t < NBLK) ? bsum[t] : 0;
    int lane = t & 63, wid = t >> 6;
    int s = v;
    #pragma unroll
    for (int off = 1; off < 64; off <<= 1) {
        int u = __shfl_up(s, off);
        if (lane >= off) s += u;
    }
    __shared__ int wsum[4];
    if (lane == 63) wsum[wid] = s;
    __syncthreads();
    int wpre = 0;
    #pragma unroll
    for (int w = 0; w < 4; ++w) if (w < wid) wpre += wsum[w];
    if (t < NBLK) bsum[t] = s + wpre - v;
}

__global__ __launch_bounds__(256) void scan3_kernel(const int* __restrict__ part,
                                                    const int* __restrict__ bsum,
                                                    int* __restrict__ cursor,
                                                    int* __restrict__ rowptr) {
    int i = blockIdx.x * 256 + threadIdx.x;
    if (i < N_NODES) {
        int v = part[i] + bsum[blockIdx.x];
        cursor[i] = v;
        rowptr[i] = v;
    }
    if (blockIdx.x == 0 && threadIdx.x == 0) rowptr[N_NODES] = N_EDGES;
}

// combined scatter (round-4 proven version: ~105 us)
__global__ __launch_bounds__(256) void scatter_kernel(
    const int* __restrict__ src, const int* __restrict__ dst,
    const float* __restrict__ eattr, int* __restrict__ cursor,
    int* __restrict__ ssrc, int* __restrict__ sdst, float4* __restrict__ sea) {
    int e = blockIdx.x * 256 + threadIdx.x;
    if (e >= N_EDGES) return;
    int d = dst[e];
    int pos = atomicAdd(&cursor[d], 1);
    ssrc[pos] = src[e];
    sdst[pos] = d;
    sea[pos] = reinterpret_cast<const float4*>(eattr)[e];
}

// ---------- init: copy state + layer-0 per-node precompute ----------
__global__ __launch_bounds__(256) void init_kernel(
    const float* __restrict__ h0, const float* __restrict__ pos,
    float* __restrict__ h, float* __restrict__ x,
    const float* __restrict__ Wm1, const float* __restrict__ bm1,
    const float* __restrict__ Wx1, const float* __restrict__ bx1,
    float* __restrict__ preA, float* __restrict__ preB)
{
    __shared__ float sM[2 * F * F], sX[2 * F * F], sbm[F], sbx[F];
    int t = threadIdx.x;
    for (int i2 = t; i2 < 2 * F * F; i2 += 256) { sM[i2] = Wm1[i2]; sX[i2] = Wx1[i2]; }
    if (t < F) { sbm[t] = bm1[t]; sbx[t] = bx1[t]; }
    __syncthreads();

    int n = blockIdx.x * 256 + t;
    if (n >= N_NODES) return;

    float hv[F];
    #pragma unroll
    for (int f2 = 0; f2 < F; ++f2) { hv[f2] = h0[n * F + f2]; h[n * F + f2] = hv[f2]; }
    #pragma unroll
    for (int k = 0; k < 3; ++k) x[n * 3 + k] = pos[n * 3 + k];

    float am[F], bm_[F], ax[F], bx_[F];
    #pragma unroll
    for (int o = 0; o < F; ++o) { am[o] = sbm[o]; ax[o] = sbx[o]; bm_[o] = 0.f; bx_[o] = 0.f; }
    #pragma unroll
    for (int fi = 0; fi < F; ++fi) {
        float v = hv[fi];
        #pragma unroll
        for (int o = 0; o < F; ++o) {
            am[o]  = fmaf(v, sM[fi * F + o], am[o]);
            bm_[o] = fmaf(v, sM[(F + fi) * F + o], bm_[o]);
            ax[o]  = fmaf(v, sX[fi * F + o], ax[o]);
            bx_[o] = fmaf(v, sX[(F + fi) * F + o], bx_[o]);
        }
    }
    #pragma unroll
    for (int o = 0; o < F; ++o) {
        preA[n * PRESTRIDE + o]      = am[o];
        preA[n * PRESTRIDE + 12 + o] = ax[o];
        preB[n * PRESTRIDE + o]      = bm_[o];
        preB[n * PRESTRIDE + 12 + o] = bx_[o];
    }
    preA[n * PRESTRIDE + 11] = 0.f; preA[n * PRESTRIDE + 23] = 0.f;
    preB[n * PRESTRIDE + 11] = 0.f; preB[n * PRESTRIDE + 23] = 0.f;
}

// ---------- per-layer edge kernel: chunk-owned nodes, LDS agg, low-VGPR scalar compute ----------
__global__ __launch_bounds__(256, 4) void edge_kernel(
    const float* __restrict__ preA, const float* __restrict__ preB,
    const float* __restrict__ x,
    const int* __restrict__ rowptr,
    const int* __restrict__ ssrc, const int* __restrict__ sdst,
    const float4* __restrict__ sea,
    const float* __restrict__ Wm1,                                  // rows 22..26
    const float* __restrict__ Wm2, const float* __restrict__ bm2,
    const float* __restrict__ Wa,  const float* __restrict__ ba,
    const float* __restrict__ Wx1,                                  // rows 22..26
    const float* __restrict__ Wx2, const float* __restrict__ bx2,
    const float* __restrict__ Wx3, const float* __restrict__ bx3,
    float* __restrict__ agg_h, float* __restrict__ agg_x)
{
    __shared__ float sWm2[F * F], sWx2[F * F];
    __shared__ float sMd2[F], sMea[4 * F], sXd2[F], sXea[4 * F];
    __shared__ float sbm2[F], sWa[F], sbx2[F], sWx3[F];
    __shared__ float sba, sbx3;
    __shared__ float sAgg[CHUNK_NODES][NVALS];
    __shared__ int sE[2];
    int t = threadIdx.x;
    for (int i2 = t; i2 < F * F; i2 += 256) { sWm2[i2] = Wm2[i2]; sWx2[i2] = Wx2[i2]; }
    if (t < F) {
        sMd2[t] = Wm1[22 * F + t]; sXd2[t] = Wx1[22 * F + t];
        sbm2[t] = bm2[t]; sWa[t] = Wa[t]; sbx2[t] = bx2[t]; sWx3[t] = Wx3[t];
    }
    if (t >= 64 && t < 64 + 4 * F) {
        int k = t - 64;
        sMea[k] = Wm1[23 * F + k];
        sXea[k] = Wx1[23 * F + k];
    }
    if (t == 0) { sba = ba[0]; sbx3 = bx3[0]; }
    for (int i2 = t; i2 < CHUNK_NODES * NVALS; i2 += 256) ((float*)sAgg)[i2] = 0.f;
    int nbase = blockIdx.x * CHUNK_NODES;
    if (t == 0) { sE[0] = rowptr[nbase]; sE[1] = rowptr[nbase + CHUNK_NODES]; }
    __syncthreads();

    int estart = sE[0], eend = sE[1];
    int K = (eend - estart + 255) >> 8;
    int lane = t & 63;

    for (int k = 0; k < K; ++k) {
        int e = estart + (k << 8) + t;
        bool act = (e < eend);
        int el = act ? e : (eend - 1);

        int j = ssrc[el];   // source (random)
        int d = sdst[el];   // target (sorted, chunk-local)

        float xi0 = x[d * 3 + 0], xi1 = x[d * 3 + 1], xi2 = x[d * 3 + 2];
        float xj0 = x[j * 3 + 0], xj1 = x[j * 3 + 1], xj2 = x[j * 3 + 2];
        float dx = xj0 - xi0, dy = xj1 - xi1, dz = xj2 - xi2;
        float d2 = dx * dx + dy * dy + dz * dz;
        float4 ea = sea[el];

        float vals[NVALS];

        // ---- phase 1: msg path (uses only m-halves of pre tables) ----
        {
            const float4* pa4 = reinterpret_cast<const float4*>(preA + (size_t)d * PRESTRIDE);
            const float4* pb4 = reinterpret_cast<const float4*>(preB + (size_t)j * PRESTRIDE);
            float4 a0 = pa4[0], a1 = pa4[1], a2 = pa4[2];
            float4 b0 = pb4[0], b1 = pb4[1], b2 = pb4[2];
            float pm[12];
            pm[0] = a0.x + b0.x; pm[1] = a0.y + b0.y; pm[2] = a0.z + b0.z; pm[3] = a0.w + b0.w;
            pm[4] = a1.x + b1.x; pm[5] = a1.y + b1.y; pm[6] = a1.z + b1.z; pm[7] = a1.w + b1.w;
            pm[8] = a2.x + b2.x; pm[9] = a2.y + b2.y; pm[10] = a2.z + b2.z; pm[11] = 0.f;

            float tm[F];
            #pragma unroll
            for (int o = 0; o < F; ++o) {
                float v = pm[o];
                v = fmaf(d2,   sMd2[o],         v);
                v = fmaf(ea.x, sMea[0 * F + o], v);
                v = fmaf(ea.y, sMea[1 * F + o], v);
                v = fmaf(ea.z, sMea[2 * F + o], v);
                v = fmaf(ea.w, sMea[3 * F + o], v);
                tm[o] = siluf(v);
            }
            float m2[F];
            #pragma unroll
            for (int o = 0; o < F; ++o) m2[o] = sbm2[o];
            #pragma unroll
            for (int fi = 0; fi < F; ++fi) {
                float a = tm[fi];
                #pragma unroll
                for (int o = 0; o < F; ++o) m2[o] = fmaf(a, sWm2[fi * F + o], m2[o]);
            }
            float attn = sba;
            #pragma unroll
            for (int o = 0; o < F; ++o) { m2[o] = siluf(m2[o]); attn = fmaf(m2[o], sWa[o], attn); }
            attn = sigmf(attn);
            #pragma unroll
            for (int o = 0; o < F; ++o) vals[o] = attn * m2[o];
        }

        // ---- phase 2: phi path (x-halves of pre tables) ----
        {
            const float4* pa4 = reinterpret_cast<const float4*>(preA + (size_t)d * PRESTRIDE + 12);
            const float4* pb4 = reinterpret_cast<const float4*>(preB + (size_t)j * PRESTRIDE + 12);
            float4 a0 = pa4[0], a1 = pa4[1], a2 = pa4[2];
            float4 b0 = pb4[0], b1 = pb4[1], b2 = pb4[2];
            float px[12];
            px[0] = a0.x + b0.x; px[1] = a0.y + b0.y; px[2] = a0.z + b0.z; px[3] = a0.w + b0.w;
            px[4] = a1.x + b1.x; px[5] = a1.y + b1.y; px[6] = a1.z + b1.z; px[7] = a1.w + b1.w;
            px[8] = a2.x + b2.x; px[9] = a2.y + b2.y; px[10] = a2.z + b2.z; px[11] = 0.f;

            float tx[F];
            #pragma unroll
            for (int o = 0; o < F; ++o) {
                float v = px[o];
                v = fmaf(d2,   sXd2[o],         v);
                v = fmaf(ea.x, sXea[0 * F + o], v);
                v = fmaf(ea.y, sXea[1 * F + o], v);
                v = fmaf(ea.z, sXea[2 * F + o], v);
                v = fmaf(ea.w, sXea[3 * F + o], v);
                tx[o] = siluf(v);
            }
            float p2[F];
            #pragma unroll
            for (int o = 0; o < F; ++o) p2[o] = sbx2[o];
            #pragma unroll
            for (int fi = 0; fi < F; ++fi) {
                float a = tx[fi];
                #pragma unroll
                for (int o = 0; o < F; ++o) p2[o] = fmaf(a, sWx2[fi * F + o], p2[o]);
            }
            float phi = sbx3;
            #pragma unroll
            for (int o = 0; o < F; ++o) phi = fmaf(siluf(p2[o]), sWx3[o], phi);

            float dist = sqrtf(d2);
            float sc = phi / (dist + 1.0f);
            vals[F + 0] = (xi0 - xj0) * sc;
            vals[F + 1] = (xi1 - xj1) * sc;
            vals[F + 2] = (xi2 - xj2) * sc;
        }

        if (!act) d = -1;

        // wave-level segmented suffix reduction (keys sorted within wave)
        #pragma unroll
        for (int off = 1; off < 64; off <<= 1) {
            int du = __shfl_down(d, off);
            bool ok = (lane + off < 64) && (du == d);
            #pragma unroll
            for (int kk = 0; kk < NVALS; ++kk) {
                float up = __shfl_down(vals[kk], off);
                if (ok) vals[kk] += up;
            }
        }
        int dprev = __shfl_up(d, 1);
        bool leader = (d >= 0) && (lane == 0 || dprev != d);
        if (leader) {
            int slot = d - nbase;
            #pragma unroll
            for (int o = 0; o < NVALS; ++o) atomicAdd(&sAgg[slot][o], vals[o]);
        }
    }

    __syncthreads();
    for (int i2 = t; i2 < CHUNK_NODES * NVALS; i2 += 256) {
        int n = nbase + i2 / NVALS;
        int f = i2 % NVALS;
        float v = ((const float*)sAgg)[i2];
        if (f < F) agg_h[n * F + f] = v;
        else       agg_x[n * 3 + (f - F)] = v;
    }
}

// ---------- node update + fused precompute for next layer ----------
__global__ __launch_bounds__(256) void node_kernel(
    float* __restrict__ h, float* __restrict__ x,
    const float* __restrict__ agg_h, const float* __restrict__ agg_x,
    const float* __restrict__ Wu1, const float* __restrict__ bu1,
    const float* __restrict__ Wu2, const float* __restrict__ bu2,
    const float* __restrict__ Wm1n, const float* __restrict__ bm1n,
    const float* __restrict__ Wx1n, const float* __restrict__ bx1n,
    float* __restrict__ preA, float* __restrict__ preB, int has_next)
{
    __shared__ float sWu1[2 * F * F], sWu2[F * F], sbu1[F], sbu2[F];
    __shared__ float sM[2 * F * F], sX[2 * F * F], sbm[F], sbx[F];
    int t = threadIdx.x;
    for (int i2 = t; i2 < 2 * F * F; i2 += 256) sWu1[i2] = Wu1[i2];
    for (int i2 = t; i2 < F * F; i2 += 256)     sWu2[i2] = Wu2[i2];
    if (t < F) { sbu1[t] = bu1[t]; sbu2[t] = bu2[t]; }
    if (has_next) {
        for (int i2 = t; i2 < 2 * F * F; i2 += 256) { sM[i2] = Wm1n[i2]; sX[i2] = Wx1n[i2]; }
        if (t < F) { sbm[t] = bm1n[t]; sbx[t] = bx1n[t]; }
    }
    __syncthreads();

    int n = blockIdx.x * 256 + t;
    if (n >= N_NODES) return;

    float in[2 * F];
    #pragma unroll
    for (int f2 = 0; f2 < F; ++f2) in[f2] = h[n * F + f2];
    #pragma unroll
    for (int f2 = 0; f2 < F; ++f2) in[F + f2] = agg_h[n * F + f2];

    float u[F];
    #pragma unroll
    for (int o = 0; o < F; ++o) u[o] = sbu1[o];
    #pragma unroll
    for (int fi = 0; fi < 2 * F; ++fi) {
        float fv = in[fi];
        #pragma unroll
        for (int o = 0; o < F; ++o) u[o] = fmaf(fv, sWu1[fi * F + o], u[o]);
    }
    #pragma unroll
    for (int o = 0; o < F; ++o) u[o] = siluf(u[o]);

    float hn[F];
    #pragma unroll
    for (int o = 0; o < F; ++o) hn[o] = in[o] + sbu2[o];
    #pragma unroll
    for (int fi = 0; fi < F; ++fi) {
        float fv = u[fi];
        #pragma unroll
        for (int o = 0; o < F; ++o) hn[o] = fmaf(fv, sWu2[fi * F + o], hn[o]);
    }

    #pragma unroll
    for (int f2 = 0; f2 < F; ++f2) h[n * F + f2] = hn[f2];
    #pragma unroll
    for (int k = 0; k < 3; ++k) x[n * 3 + k] += agg_x[n * 3 + k];

    if (has_next) {
        float am[F], bm_[F], ax[F], bx_[F];
        #pragma unroll
        for (int o = 0; o < F; ++o) { am[o] = sbm[o]; ax[o] = sbx[o]; bm_[o] = 0.f; bx_[o] = 0.f; }
        #pragma unroll
        for (int fi = 0; fi < F; ++fi) {
            float v = hn[fi];
            #pragma unroll
            for (int o = 0; o < F; ++o) {
                am[o]  = fmaf(v, sM[fi * F + o], am[o]);
                bm_[o] = fmaf(v, sM[(F + fi) * F + o], bm_[o]);
                ax[o]  = fmaf(v, sX[fi * F + o], ax[o]);
                bx_[o] = fmaf(v, sX[(F + fi) * F + o], bx_[o]);
            }
        }
        #pragma unroll
        for (int o = 0; o < F; ++o) {
            preA[n * PRESTRIDE + o]      = am[o];
            preA[n * PRESTRIDE + 12 + o] = ax[o];
            preB[n * PRESTRIDE + o]      = bm_[o];
            preB[n * PRESTRIDE + 12 + o] = bx_[o];
        }
        preA[n * PRESTRIDE + 11] = 0.f; preA[n * PRESTRIDE + 23] = 0.f;
        preB[n * PRESTRIDE + 11] = 0.f; preB[n * PRESTRIDE + 23] = 0.f;
    }
}

// ---------- pool ----------
__global__ __launch_bounds__(256) void pool_kernel(
    const float* __restrict__ h, const int* __restrict__ batch,
    float* __restrict__ gsum, float* __restrict__ gcnt)
{
    int n = blockIdx.x * blockDim.x + threadIdx.x;
    int lane = threadIdx.x & 63;
    bool valid = (n < N_NODES);
    int g = valid ? batch[n] : -1;
    float vals[F + 1];
    #pragma unroll
    for (int f2 = 0; f2 < F; ++f2) vals[f2] = valid ? h[n * F + f2] : 0.0f;
    vals[F] = valid ? 1.0f : 0.0f;

    #pragma unroll
    for (int off = 1; off < 64; off <<= 1) {
        int gu = __shfl_down(g, off);
        bool ok = (lane + off < 64) && (gu == g);
        #pragma unroll
        for (int k = 0; k < F + 1; ++k) {
            float up = __shfl_down(vals[k], off);
            if (ok) vals[k] += up;
        }
    }
    int gprev = __shfl_up(g, 1);
    if (valid && (lane == 0 || gprev != g)) {
        #pragma unroll
        for (int f2 = 0; f2 < F; ++f2) unsafeAtomicAdd(&gsum[g * F + f2], vals[f2]);
        unsafeAtomicAdd(&gcnt[g], vals[F]);
    }
}

__global__ void head_kernel(const float* __restrict__ gsum, const float* __restrict__ gcnt,
                            const float* __restrict__ Wp, const float* __restrict__ bp,
                            float* __restrict__ out)
{
    int g = blockIdx.x * blockDim.x + threadIdx.x;
    if (g >= NGRAPH) return;
    float c = fmaxf(gcnt[g], 1.0f);
    float inv = 1.0f / c;
    float acc = bp[0];
    #pragma unroll
    for (int f2 = 0; f2 < F; ++f2) acc = fmaf(gsum[g * F + f2] * inv, Wp[f2], acc);
    out[g] = acc;
}

extern "C" void kernel_launch(void* const* d_in, const int* in_sizes, int n_in,
                              void* d_out, int out_size, void* d_ws, size_t ws_size,
                              hipStream_t stream)
{
    const float* h0    = (const float*)d_in[0];
    const float* pos   = (const float*)d_in[1];
    const int*   eidx  = (const int*)d_in[2];
    const float* eattr = (const float*)d_in[3];
    const int*   batch = (const int*)d_in[4];
    const float* Wm1 = (const float*)d_in[5];
    const float* bm1 = (const float*)d_in[6];
    const float* Wm2 = (const float*)d_in[7];
    const float* bm2 = (const float*)d_in[8];
    const float* Wa  = (const float*)d_in[9];
    const float* ba  = (const float*)d_in[10];
    const float* Wu1 = (const float*)d_in[11];
    const float* bu1 = (const float*)d_in[12];
    const float* Wu2 = (const float*)d_in[13];
    const float* bu2 = (const float*)d_in[14];
    const float* Wx1 = (const float*)d_in[15];
    const float* bx1 = (const float*)d_in[16];
    const float* Wx2 = (const float*)d_in[17];
    const float* bx2 = (const float*)d_in[18];
    const float* Wx3 = (const float*)d_in[19];
    const float* bx3 = (const float*)d_in[20];
    const float* Wp  = (const float*)d_in[21];
    const float* bp  = (const float*)d_in[22];

    char* base = (char*)d_ws;
    float4* sea  = (float4*)base;                         base += (size_t)N_EDGES * 16;
    float* preA  = (float*)base;                          base += (size_t)N_NODES * PRESTRIDE * 4;
    float* preB  = (float*)base;                          base += (size_t)N_NODES * PRESTRIDE * 4;
    float* h_cur = (float*)base;                          base += (size_t)N_NODES * F * 4;
    float* x_cur = (float*)base;                          base += (size_t)N_NODES * 3 * 4;
    float* agg_h = (float*)base;                          base += (size_t)N_NODES * F * 4;
    float* agg_x = (float*)base;                          base += (size_t)N_NODES * 3 * 4;
    float* gsum  = (float*)base;                          base += (size_t)NGRAPH * F * 4;
    float* gcnt  = (float*)base;                          base += (size_t)NGRAPH * 4;
    int*   deg   = (int*)base;                            base += (size_t)N_NODES * 4;
    int*   part  = (int*)base;                            base += (size_t)N_NODES * 4;
    int*   bsum  = (int*)base;                            base += (size_t)256 * 4;
    int*   cursor= (int*)base;                            base += (size_t)N_NODES * 4;
    int*   rowptr= (int*)base;                            base += (size_t)(N_NODES + 1) * 4;
    int*   ssrc  = (int*)base;                            base += (size_t)N_EDGES * 4;
    int*   sdst  = (int*)base;                            base += (size_t)N_EDGES * 4;

    const int* src = eidx;            // edge_index[0]
    const int* dst = eidx + N_EDGES;  // edge_index[1]

    // one-time: counting sort of edges by dst
    hipMemsetAsync(deg, 0, (size_t)N_NODES * sizeof(int), stream);
    hist_kernel<<<(N_EDGES + 255) / 256, 256, 0, stream>>>(dst, deg);
    scan1_kernel<<<NBLK, 256, 0, stream>>>(deg, part, bsum);
    scan2_kernel<<<1, 256, 0, stream>>>(bsum);
    scan3_kernel<<<NBLK, 256, 0, stream>>>(part, bsum, cursor, rowptr);
    scatter_kernel<<<(N_EDGES + 255) / 256, 256, 0, stream>>>(
        src, dst, eattr, cursor, ssrc, sdst, sea);

    init_kernel<<<NBLK, 256, 0, stream>>>(h0, pos, h_cur, x_cur,
                                          Wm1, bm1, Wx1, bx1, preA, preB);

    for (int l = 0; l < NLAYERS; ++l) {
        edge_kernel<<<NCHUNK, 256, 0, stream>>>(
            preA, preB, x_cur, rowptr, ssrc, sdst, sea,
            Wm1 + l * FEAT * F,
            Wm2 + l * F * F,    bm2 + l * F,
            Wa + l * F,         ba + l,
            Wx1 + l * FEAT * F,
            Wx2 + l * F * F,    bx2 + l * F,
            Wx3 + l * F,        bx3 + l,
            agg_h, agg_x);
        int nl = l + 1;
        int has_next = (nl < NLAYERS) ? 1 : 0;
        int wl = has_next ? nl : l;
        node_kernel<<<NBLK, 256, 0, stream>>>(
            h_cur, x_cur, agg_h, agg_x,
            Wu1 + l * 2 * F * F, bu1 + l * F,
            Wu2 + l * F * F,     bu2 + l * F,
            Wm1 + wl * FEAT * F, bm1 + wl * F,
            Wx1 + wl * FEAT * F, bx1 + wl * F,
            preA, preB, has_next);
    }

    hipMemsetAsync(gsum, 0, (size_t)(NGRAPH * F + NGRAPH) * sizeof(float), stream);
    pool_kernel<<<(N_NODES + 255) / 256, 256, 0, stream>>>(h_cur, batch, gsum, gcnt);
    head_kernel<<<2, 256, 0, stream>>>(gsum, gcnt, Wp, bp, (float*)d_out);
}

// Round 9
// 1159.048 us; speedup vs baseline: 2.6438x; 2.6438x over previous
//
#include <hip/hip_runtime.h>

#define N_NODES 50000
#define N_EDGES 1600000
#define F 11
#define FEAT 27   // 2F + 1 + ED
#define NLAYERS 4
#define NGRAPH 500
#define NVALS 14        // 11 msg_h + 3 msg_x
#define PRESTRIDE 24    // padded pre-table row: m[0..12), x[12..24)
#define NBLK 196        // ceil(N_NODES/256)
#define CHUNK_NODES 25  // nodes per edge-kernel block
#define NCHUNK 2000     // N_NODES / CHUNK_NODES

__device__ __forceinline__ float siluf(float v) { return v * (1.0f / (1.0f + __expf(-v))); }
__device__ __forceinline__ float sigmf(float v) { return 1.0f / (1.0f + __expf(-v)); }

// ---------- one-time edge sort by dst (counting sort) ----------
__global__ __launch_bounds__(256) void hist_kernel(const int* __restrict__ dst,
                                                   int* __restrict__ deg) {
    int e = blockIdx.x * 256 + threadIdx.x;
    if (e < N_EDGES) atomicAdd(&deg[dst[e]], 1);
}

__global__ __launch_bounds__(256) void scan1_kernel(const int* __restrict__ deg,
                                                    int* __restrict__ part,
                                                    int* __restrict__ bsum) {
    int t = threadIdx.x;
    int i = blockIdx.x * 256 + t;
    int v = (i < N_NODES) ? deg[i] : 0;
    int lane = t & 63, wid = t >> 6;
    int s = v;
    #pragma unroll
    for (int off = 1; off < 64; off <<= 1) {
        int u = __shfl_up(s, off);
        if (lane >= off) s += u;
    }
    __shared__ int wsum[4];
    if (lane == 63) wsum[wid] = s;
    __syncthreads();
    int wpre = 0;
    #pragma unroll
    for (int w = 0; w < 4; ++w) if (w < wid) wpre += wsum[w];
    if (i < N_NODES) part[i] = s + wpre - v;
    if (t == 255) bsum[blockIdx.x] = s + wpre;
}

__global__ __launch_bounds__(256) void scan2_kernel(int* __restrict__ bsum) {
    int t = threadIdx.x;
    int v = (t < NBLK) ? bsum[t] : 0;
    int lane = t & 63, wid = t >> 6;
    int s = v;
    #pragma unroll
    for (int off = 1; off < 64; off <<= 1) {
        int u = __shfl_up(s, off);
        if (lane >= off) s += u;
    }
    __shared__ int wsum[4];
    if (lane == 63) wsum[wid] = s;
    __syncthreads();
    int wpre = 0;
    #pragma unroll
    for (int w = 0; w < 4; ++w) if (w < wid) wpre += wsum[w];
    if (t < NBLK) bsum[t] = s + wpre - v;
}

__global__ __launch_bounds__(256) void scan3_kernel(const int* __restrict__ part,
                                                    const int* __restrict__ bsum,
                                                    int* __restrict__ cursor,
                                                    int* __restrict__ rowptr) {
    int i = blockIdx.x * 256 + threadIdx.x;
    if (i < N_NODES) {
        int v = part[i] + bsum[blockIdx.x];
        cursor[i] = v;
        rowptr[i] = v;
    }
    if (blockIdx.x == 0 && threadIdx.x == 0) rowptr[N_NODES] = N_EDGES;
}

// combined scatter (round-4 proven version: ~105 us)
__global__ __launch_bounds__(256) void scatter_kernel(
    const int* __restrict__ src, const int* __restrict__ dst,
    const float* __restrict__ eattr, int* __restrict__ cursor,
    int* __restrict__ ssrc, int* __restrict__ sdst, float4* __restrict__ sea) {
    int e = blockIdx.x * 256 + threadIdx.x;
    if (e >= N_EDGES) return;
    int d = dst[e];
    int pos = atomicAdd(&cursor[d], 1);
    ssrc[pos] = src[e];
    sdst[pos] = d;
    sea[pos] = reinterpret_cast<const float4*>(eattr)[e];
}

// ---------- init: copy state + layer-0 per-node precompute ----------
__global__ __launch_bounds__(256) void init_kernel(
    const float* __restrict__ h0, const float* __restrict__ pos,
    float* __restrict__ h, float* __restrict__ x,
    const float* __restrict__ Wm1, const float* __restrict__ bm1,
    const float* __restrict__ Wx1, const float* __restrict__ bx1,
    float* __restrict__ preA, float* __restrict__ preB)
{
    __shared__ float sM[2 * F * F], sX[2 * F * F], sbm[F], sbx[F];
    int t = threadIdx.x;
    for (int i2 = t; i2 < 2 * F * F; i2 += 256) { sM[i2] = Wm1[i2]; sX[i2] = Wx1[i2]; }
    if (t < F) { sbm[t] = bm1[t]; sbx[t] = bx1[t]; }
    __syncthreads();

    int n = blockIdx.x * 256 + t;
    if (n >= N_NODES) return;

    float hv[F];
    #pragma unroll
    for (int f2 = 0; f2 < F; ++f2) { hv[f2] = h0[n * F + f2]; h[n * F + f2] = hv[f2]; }
    #pragma unroll
    for (int k = 0; k < 3; ++k) x[n * 3 + k] = pos[n * 3 + k];

    float am[F], bm_[F], ax[F], bx_[F];
    #pragma unroll
    for (int o = 0; o < F; ++o) { am[o] = sbm[o]; ax[o] = sbx[o]; bm_[o] = 0.f; bx_[o] = 0.f; }
    #pragma unroll
    for (int fi = 0; fi < F; ++fi) {
        float v = hv[fi];
        #pragma unroll
        for (int o = 0; o < F; ++o) {
            am[o]  = fmaf(v, sM[fi * F + o], am[o]);
            bm_[o] = fmaf(v, sM[(F + fi) * F + o], bm_[o]);
            ax[o]  = fmaf(v, sX[fi * F + o], ax[o]);
            bx_[o] = fmaf(v, sX[(F + fi) * F + o], bx_[o]);
        }
    }
    #pragma unroll
    for (int o = 0; o < F; ++o) {
        preA[n * PRESTRIDE + o]      = am[o];
        preA[n * PRESTRIDE + 12 + o] = ax[o];
        preB[n * PRESTRIDE + o]      = bm_[o];
        preB[n * PRESTRIDE + 12 + o] = bx_[o];
    }
    preA[n * PRESTRIDE + 11] = 0.f; preA[n * PRESTRIDE + 23] = 0.f;
    preB[n * PRESTRIDE + 11] = 0.f; preB[n * PRESTRIDE + 23] = 0.f;
}

// ---------- per-layer edge kernel: chunk-owned nodes, LDS agg, low-VGPR scalar compute ----------
__global__ __launch_bounds__(256) void edge_kernel(
    const float* __restrict__ preA, const float* __restrict__ preB,
    const float* __restrict__ x,
    const int* __restrict__ rowptr,
    const int* __restrict__ ssrc, const int* __restrict__ sdst,
    const float4* __restrict__ sea,
    const float* __restrict__ Wm1,                                  // rows 22..26
    const float* __restrict__ Wm2, const float* __restrict__ bm2,
    const float* __restrict__ Wa,  const float* __restrict__ ba,
    const float* __restrict__ Wx1,                                  // rows 22..26
    const float* __restrict__ Wx2, const float* __restrict__ bx2,
    const float* __restrict__ Wx3, const float* __restrict__ bx3,
    float* __restrict__ agg_h, float* __restrict__ agg_x)
{
    __shared__ float sWm2[F * F], sWx2[F * F];
    __shared__ float sMd2[F], sMea[4 * F], sXd2[F], sXea[4 * F];
    __shared__ float sbm2[F], sWa[F], sbx2[F], sWx3[F];
    __shared__ float sba, sbx3;
    __shared__ float sAgg[CHUNK_NODES][NVALS];
    __shared__ int sE[2];
    int t = threadIdx.x;
    for (int i2 = t; i2 < F * F; i2 += 256) { sWm2[i2] = Wm2[i2]; sWx2[i2] = Wx2[i2]; }
    if (t < F) {
        sMd2[t] = Wm1[22 * F + t]; sXd2[t] = Wx1[22 * F + t];
        sbm2[t] = bm2[t]; sWa[t] = Wa[t]; sbx2[t] = bx2[t]; sWx3[t] = Wx3[t];
    }
    if (t >= 64 && t < 64 + 4 * F) {
        int k = t - 64;
        sMea[k] = Wm1[23 * F + k];
        sXea[k] = Wx1[23 * F + k];
    }
    if (t == 0) { sba = ba[0]; sbx3 = bx3[0]; }
    for (int i2 = t; i2 < CHUNK_NODES * NVALS; i2 += 256) ((float*)sAgg)[i2] = 0.f;
    int nbase = blockIdx.x * CHUNK_NODES;
    if (t == 0) { sE[0] = rowptr[nbase]; sE[1] = rowptr[nbase + CHUNK_NODES]; }
    __syncthreads();

    int estart = sE[0], eend = sE[1];
    int K = (eend - estart + 255) >> 8;
    int lane = t & 63;

    for (int k = 0; k < K; ++k) {
        int e = estart + (k << 8) + t;
        bool act = (e < eend);
        int el = act ? e : (eend - 1);

        int j = ssrc[el];   // source (random)
        int d = sdst[el];   // target (sorted, chunk-local)

        float xi0 = x[d * 3 + 0], xi1 = x[d * 3 + 1], xi2 = x[d * 3 + 2];
        float xj0 = x[j * 3 + 0], xj1 = x[j * 3 + 1], xj2 = x[j * 3 + 2];
        float dx = xj0 - xi0, dy = xj1 - xi1, dz = xj2 - xi2;
        float d2 = dx * dx + dy * dy + dz * dz;
        float4 ea = sea[el];

        float vals[NVALS];

        // ---- phase 1: msg path (uses only m-halves of pre tables) ----
        {
            const float4* pa4 = reinterpret_cast<const float4*>(preA + (size_t)d * PRESTRIDE);
            const float4* pb4 = reinterpret_cast<const float4*>(preB + (size_t)j * PRESTRIDE);
            float4 a0 = pa4[0], a1 = pa4[1], a2 = pa4[2];
            float4 b0 = pb4[0], b1 = pb4[1], b2 = pb4[2];
            float pm[12];
            pm[0] = a0.x + b0.x; pm[1] = a0.y + b0.y; pm[2] = a0.z + b0.z; pm[3] = a0.w + b0.w;
            pm[4] = a1.x + b1.x; pm[5] = a1.y + b1.y; pm[6] = a1.z + b1.z; pm[7] = a1.w + b1.w;
            pm[8] = a2.x + b2.x; pm[9] = a2.y + b2.y; pm[10] = a2.z + b2.z; pm[11] = 0.f;

            float tm[F];
            #pragma unroll
            for (int o = 0; o < F; ++o) {
                float v = pm[o];
                v = fmaf(d2,   sMd2[o],         v);
                v = fmaf(ea.x, sMea[0 * F + o], v);
                v = fmaf(ea.y, sMea[1 * F + o], v);
                v = fmaf(ea.z, sMea[2 * F + o], v);
                v = fmaf(ea.w, sMea[3 * F + o], v);
                tm[o] = siluf(v);
            }
            float m2[F];
            #pragma unroll
            for (int o = 0; o < F; ++o) m2[o] = sbm2[o];
            #pragma unroll
            for (int fi = 0; fi < F; ++fi) {
                float a = tm[fi];
                #pragma unroll
                for (int o = 0; o < F; ++o) m2[o] = fmaf(a, sWm2[fi * F + o], m2[o]);
            }
            float attn = sba;
            #pragma unroll
            for (int o = 0; o < F; ++o) { m2[o] = siluf(m2[o]); attn = fmaf(m2[o], sWa[o], attn); }
            attn = sigmf(attn);
            #pragma unroll
            for (int o = 0; o < F; ++o) vals[o] = attn * m2[o];
        }

        // ---- phase 2: phi path (x-halves of pre tables) ----
        {
            const float4* pa4 = reinterpret_cast<const float4*>(preA + (size_t)d * PRESTRIDE + 12);
            const float4* pb4 = reinterpret_cast<const float4*>(preB + (size_t)j * PRESTRIDE + 12);
            float4 a0 = pa4[0], a1 = pa4[1], a2 = pa4[2];
            float4 b0 = pb4[0], b1 = pb4[1], b2 = pb4[2];
            float px[12];
            px[0] = a0.x + b0.x; px[1] = a0.y + b0.y; px[2] = a0.z + b0.z; px[3] = a0.w + b0.w;
            px[4] = a1.x + b1.x; px[5] = a1.y + b1.y; px[6] = a1.z + b1.z; px[7] = a1.w + b1.w;
            px[8] = a2.x + b2.x; px[9] = a2.y + b2.y; px[10] = a2.z + b2.z; px[11] = 0.f;

            float tx[F];
            #pragma unroll
            for (int o = 0; o < F; ++o) {
                float v = px[o];
                v = fmaf(d2,   sXd2[o],         v);
                v = fmaf(ea.x, sXea[0 * F + o], v);
                v = fmaf(ea.y, sXea[1 * F + o], v);
                v = fmaf(ea.z, sXea[2 * F + o], v);
                v = fmaf(ea.w, sXea[3 * F + o], v);
                tx[o] = siluf(v);
            }
            float p2[F];
            #pragma unroll
            for (int o = 0; o < F; ++o) p2[o] = sbx2[o];
            #pragma unroll
            for (int fi = 0; fi < F; ++fi) {
                float a = tx[fi];
                #pragma unroll
                for (int o = 0; o < F; ++o) p2[o] = fmaf(a, sWx2[fi * F + o], p2[o]);
            }
            float phi = sbx3;
            #pragma unroll
            for (int o = 0; o < F; ++o) phi = fmaf(siluf(p2[o]), sWx3[o], phi);

            float dist = sqrtf(d2);
            float sc = phi / (dist + 1.0f);
            vals[F + 0] = (xi0 - xj0) * sc;
            vals[F + 1] = (xi1 - xj1) * sc;
            vals[F + 2] = (xi2 - xj2) * sc;
        }

        if (!act) d = -1;

        // wave-level segmented suffix reduction (keys sorted within wave)
        #pragma unroll
        for (int off = 1; off < 64; off <<= 1) {
            int du = __shfl_down(d, off);
            bool ok = (lane + off < 64) && (du == d);
            #pragma unroll
            for (int kk = 0; kk < NVALS; ++kk) {
                float up = __shfl_down(vals[kk], off);
                if (ok) vals[kk] += up;
            }
        }
        int dprev = __shfl_up(d, 1);
        bool leader = (d >= 0) && (lane == 0 || dprev != d);
        if (leader) {
            int slot = d - nbase;
            #pragma unroll
            for (int o = 0; o < NVALS; ++o) atomicAdd(&sAgg[slot][o], vals[o]);
        }
    }

    __syncthreads();
    for (int i2 = t; i2 < CHUNK_NODES * NVALS; i2 += 256) {
        int n = nbase + i2 / NVALS;
        int f = i2 % NVALS;
        float v = ((const float*)sAgg)[i2];
        if (f < F) agg_h[n * F + f] = v;
        else       agg_x[n * 3 + (f - F)] = v;
    }
}

// ---------- node update + fused precompute for next layer ----------
__global__ __launch_bounds__(256) void node_kernel(
    float* __restrict__ h, float* __restrict__ x,
    const float* __restrict__ agg_h, const float* __restrict__ agg_x,
    const float* __restrict__ Wu1, const float* __restrict__ bu1,
    const float* __restrict__ Wu2, const float* __restrict__ bu2,
    const float* __restrict__ Wm1n, const float* __restrict__ bm1n,
    const float* __restrict__ Wx1n, const float* __restrict__ bx1n,
    float* __restrict__ preA, float* __restrict__ preB, int has_next)
{
    __shared__ float sWu1[2 * F * F], sWu2[F * F], sbu1[F], sbu2[F];
    __shared__ float sM[2 * F * F], sX[2 * F * F], sbm[F], sbx[F];
    int t = threadIdx.x;
    for (int i2 = t; i2 < 2 * F * F; i2 += 256) sWu1[i2] = Wu1[i2];
    for (int i2 = t; i2 < F * F; i2 += 256)     sWu2[i2] = Wu2[i2];
    if (t < F) { sbu1[t] = bu1[t]; sbu2[t] = bu2[t]; }
    if (has_next) {
        for (int i2 = t; i2 < 2 * F * F; i2 += 256) { sM[i2] = Wm1n[i2]; sX[i2] = Wx1n[i2]; }
        if (t < F) { sbm[t] = bm1n[t]; sbx[t] = bx1n[t]; }
    }
    __syncthreads();

    int n = blockIdx.x * 256 + t;
    if (n >= N_NODES) return;

    float in[2 * F];
    #pragma unroll
    for (int f2 = 0; f2 < F; ++f2) in[f2] = h[n * F + f2];
    #pragma unroll
    for (int f2 = 0; f2 < F; ++f2) in[F + f2] = agg_h[n * F + f2];

    float u[F];
    #pragma unroll
    for (int o = 0; o < F; ++o) u[o] = sbu1[o];
    #pragma unroll
    for (int fi = 0; fi < 2 * F; ++fi) {
        float fv = in[fi];
        #pragma unroll
        for (int o = 0; o < F; ++o) u[o] = fmaf(fv, sWu1[fi * F + o], u[o]);
    }
    #pragma unroll
    for (int o = 0; o < F; ++o) u[o] = siluf(u[o]);

    float hn[F];
    #pragma unroll
    for (int o = 0; o < F; ++o) hn[o] = in[o] + sbu2[o];
    #pragma unroll
    for (int fi = 0; fi < F; ++fi) {
        float fv = u[fi];
        #pragma unroll
        for (int o = 0; o < F; ++o) hn[o] = fmaf(fv, sWu2[fi * F + o], hn[o]);
    }

    #pragma unroll
    for (int f2 = 0; f2 < F; ++f2) h[n * F + f2] = hn[f2];
    #pragma unroll
    for (int k = 0; k < 3; ++k) x[n * 3 + k] += agg_x[n * 3 + k];

    if (has_next) {
        float am[F], bm_[F], ax[F], bx_[F];
        #pragma unroll
        for (int o = 0; o < F; ++o) { am[o] = sbm[o]; ax[o] = sbx[o]; bm_[o] = 0.f; bx_[o] = 0.f; }
        #pragma unroll
        for (int fi = 0; fi < F; ++fi) {
            float v = hn[fi];
            #pragma unroll
            for (int o = 0; o < F; ++o) {
                am[o]  = fmaf(v, sM[fi * F + o], am[o]);
                bm_[o] = fmaf(v, sM[(F + fi) * F + o], bm_[o]);
                ax[o]  = fmaf(v, sX[fi * F + o], ax[o]);
                bx_[o] = fmaf(v, sX[(F + fi) * F + o], bx_[o]);
            }
        }
        #pragma unroll
        for (int o = 0; o < F; ++o) {
            preA[n * PRESTRIDE + o]      = am[o];
            preA[n * PRESTRIDE + 12 + o] = ax[o];
            preB[n * PRESTRIDE + o]      = bm_[o];
            preB[n * PRESTRIDE + 12 + o] = bx_[o];
        }
        preA[n * PRESTRIDE + 11] = 0.f; preA[n * PRESTRIDE + 23] = 0.f;
        preB[n * PRESTRIDE + 11] = 0.f; preB[n * PRESTRIDE + 23] = 0.f;
    }
}

// ---------- pool ----------
__global__ __launch_bounds__(256) void pool_kernel(
    const float* __restrict__ h, const int* __restrict__ batch,
    float* __restrict__ gsum, float* __restrict__ gcnt)
{
    int n = blockIdx.x * blockDim.x + threadIdx.x;
    int lane = threadIdx.x & 63;
    bool valid = (n < N_NODES);
    int g = valid ? batch[n] : -1;
    float vals[F + 1];
    #pragma unroll
    for (int f2 = 0; f2 < F; ++f2) vals[f2] = valid ? h[n * F + f2] : 0.0f;
    vals[F] = valid ? 1.0f : 0.0f;

    #pragma unroll
    for (int off = 1; off < 64; off <<= 1) {
        int gu = __shfl_down(g, off);
        bool ok = (lane + off < 64) && (gu == g);
        #pragma unroll
        for (int k = 0; k < F + 1; ++k) {
            float up = __shfl_down(vals[k], off);
            if (ok) vals[k] += up;
        }
    }
    int gprev = __shfl_up(g, 1);
    if (valid && (lane == 0 || gprev != g)) {
        #pragma unroll
        for (int f2 = 0; f2 < F; ++f2) unsafeAtomicAdd(&gsum[g * F + f2], vals[f2]);
        unsafeAtomicAdd(&gcnt[g], vals[F]);
    }
}

__global__ void head_kernel(const float* __restrict__ gsum, const float* __restrict__ gcnt,
                            const float* __restrict__ Wp, const float* __restrict__ bp,
                            float* __restrict__ out)
{
    int g = blockIdx.x * blockDim.x + threadIdx.x;
    if (g >= NGRAPH) return;
    float c = fmaxf(gcnt[g], 1.0f);
    float inv = 1.0f / c;
    float acc = bp[0];
    #pragma unroll
    for (int f2 = 0; f2 < F; ++f2) acc = fmaf(gsum[g * F + f2] * inv, Wp[f2], acc);
    out[g] = acc;
}

extern "C" void kernel_launch(void* const* d_in, const int* in_sizes, int n_in,
                              void* d_out, int out_size, void* d_ws, size_t ws_size,
                              hipStream_t stream)
{
    const float* h0    = (const float*)d_in[0];
    const float* pos   = (const float*)d_in[1];
    const int*   eidx  = (const int*)d_in[2];
    const float* eattr = (const float*)d_in[3];
    const int*   batch = (const int*)d_in[4];
    const float* Wm1 = (const float*)d_in[5];
    const float* bm1 = (const float*)d_in[6];
    const float* Wm2 = (const float*)d_in[7];
    const float* bm2 = (const float*)d_in[8];
    const float* Wa  = (const float*)d_in[9];
    const float* ba  = (const float*)d_in[10];
    const float* Wu1 = (const float*)d_in[11];
    const float* bu1 = (const float*)d_in[12];
    const float* Wu2 = (const float*)d_in[13];
    const float* bu2 = (const float*)d_in[14];
    const float* Wx1 = (const float*)d_in[15];
    const float* bx1 = (const float*)d_in[16];
    const float* Wx2 = (const float*)d_in[17];
    const float* bx2 = (const float*)d_in[18];
    const float* Wx3 = (const float*)d_in[19];
    const float* bx3 = (const float*)d_in[20];
    const float* Wp  = (const float*)d_in[21];
    const float* bp  = (const float*)d_in[22];

    char* base = (char*)d_ws;
    float4* sea  = (float4*)base;                         base += (size_t)N_EDGES * 16;
    float* preA  = (float*)base;                          base += (size_t)N_NODES * PRESTRIDE * 4;
    float* preB  = (float*)base;                          base += (size_t)N_NODES * PRESTRIDE * 4;
    float* h_cur = (float*)base;                          base += (size_t)N_NODES * F * 4;
    float* x_cur = (float*)base;                          base += (size_t)N_NODES * 3 * 4;
    float* agg_h = (float*)base;                          base += (size_t)N_NODES * F * 4;
    float* agg_x = (float*)base;                          base += (size_t)N_NODES * 3 * 4;
    float* gsum  = (float*)base;                          base += (size_t)NGRAPH * F * 4;
    float* gcnt  = (float*)base;                          base += (size_t)NGRAPH * 4;
    int*   deg   = (int*)base;                            base += (size_t)N_NODES * 4;
    int*   part  = (int*)base;                            base += (size_t)N_NODES * 4;
    int*   bsum  = (int*)base;                            base += (size_t)256 * 4;
    int*   cursor= (int*)base;                            base += (size_t)N_NODES * 4;
    int*   rowptr= (int*)base;                            base += (size_t)(N_NODES + 1) * 4;
    int*   ssrc  = (int*)base;                            base += (size_t)N_EDGES * 4;
    int*   sdst  = (int*)base;                            base += (size_t)N_EDGES * 4;

    const int* src = eidx;            // edge_index[0]
    const int* dst = eidx + N_EDGES;  // edge_index[1]

    // one-time: counting sort of edges by dst
    hipMemsetAsync(deg, 0, (size_t)N_NODES * sizeof(int), stream);
    hist_kernel<<<(N_EDGES + 255) / 256, 256, 0, stream>>>(dst, deg);
    scan1_kernel<<<NBLK, 256, 0, stream>>>(deg, part, bsum);
    scan2_kernel<<<1, 256, 0, stream>>>(bsum);
    scan3_kernel<<<NBLK, 256, 0, stream>>>(part, bsum, cursor, rowptr);
    scatter_kernel<<<(N_EDGES + 255) / 256, 256, 0, stream>>>(
        src, dst, eattr, cursor, ssrc, sdst, sea);

    init_kernel<<<NBLK, 256, 0, stream>>>(h0, pos, h_cur, x_cur,
                                          Wm1, bm1, Wx1, bx1, preA, preB);

    for (int l = 0; l < NLAYERS; ++l) {
        edge_kernel<<<NCHUNK, 256, 0, stream>>>(
            preA, preB, x_cur, rowptr, ssrc, sdst, sea,
            Wm1 + l * FEAT * F,
            Wm2 + l * F * F,    bm2 + l * F,
            Wa + l * F,         ba + l,
            Wx1 + l * FEAT * F,
            Wx2 + l * F * F,    bx2 + l * F,
            Wx3 + l * F,        bx3 + l,
            agg_h, agg_x);
        int nl = l + 1;
        int has_next = (nl < NLAYERS) ? 1 : 0;
        int wl = has_next ? nl : l;
        node_kernel<<<NBLK, 256, 0, stream>>>(
            h_cur, x_cur, agg_h, agg_x,
            Wu1 + l * 2 * F * F, bu1 + l * F,
            Wu2 + l * F * F,     bu2 + l * F,
            Wm1 + wl * FEAT * F, bm1 + wl * F,
            Wx1 + wl * FEAT * F, bx1 + wl * F,
            preA, preB, has_next);
    }

    hipMemsetAsync(gsum, 0, (size_t)(NGRAPH * F + NGRAPH) * sizeof(float), stream);
    pool_kernel<<<(N_NODES + 255) / 256, 256, 0, stream>>>(h_cur, batch, gsum, gcnt);
    head_kernel<<<2, 256, 0, stream>>>(gsum, gcnt, Wp, bp, (float*)d_out);
}

// Round 11
// 773.484 us; speedup vs baseline: 3.9617x; 1.4985x over previous
//
#include <hip/hip_runtime.h>

#define N_NODES 50000
#define N_EDGES 1600000
#define F 11
#define FEAT 27   // 2F + 1 + ED
#define NLAYERS 4
#define NGRAPH 500
#define NVALS 14        // 11 msg_h + 3 msg_x
#define PRESTRIDE 24    // padded pre-table row: m[0..12), x[12..24)
#define NBLK 196        // ceil(N_NODES/256)
#define CHUNK_NODES 25  // nodes per edge-kernel block
#define NCHUNK 2000     // N_NODES / CHUNK_NODES

__device__ __forceinline__ float siluf(float v) { return v * (1.0f / (1.0f + __expf(-v))); }
__device__ __forceinline__ float sigmf(float v) { return 1.0f / (1.0f + __expf(-v)); }

// ---------- one-time edge sort by dst (counting sort) ----------
__global__ __launch_bounds__(256) void hist_kernel(const int* __restrict__ dst,
                                                   int* __restrict__ deg) {
    int e = blockIdx.x * 256 + threadIdx.x;
    if (e < N_EDGES) atomicAdd(&deg[dst[e]], 1);
}

__global__ __launch_bounds__(256) void scan1_kernel(const int* __restrict__ deg,
                                                    int* __restrict__ part,
                                                    int* __restrict__ bsum) {
    int t = threadIdx.x;
    int i = blockIdx.x * 256 + t;
    int v = (i < N_NODES) ? deg[i] : 0;
    int lane = t & 63, wid = t >> 6;
    int s = v;
    #pragma unroll
    for (int off = 1; off < 64; off <<= 1) {
        int u = __shfl_up(s, off);
        if (lane >= off) s += u;
    }
    __shared__ int wsum[4];
    if (lane == 63) wsum[wid] = s;
    __syncthreads();
    int wpre = 0;
    #pragma unroll
    for (int w = 0; w < 4; ++w) if (w < wid) wpre += wsum[w];
    if (i < N_NODES) part[i] = s + wpre - v;
    if (t == 255) bsum[blockIdx.x] = s + wpre;
}

__global__ __launch_bounds__(256) void scan2_kernel(int* __restrict__ bsum) {
    int t = threadIdx.x;
    int v = (t < NBLK) ? bsum[t] : 0;
    int lane = t & 63, wid = t >> 6;
    int s = v;
    #pragma unroll
    for (int off = 1; off < 64; off <<= 1) {
        int u = __shfl_up(s, off);
        if (lane >= off) s += u;
    }
    __shared__ int wsum[4];
    if (lane == 63) wsum[wid] = s;
    __syncthreads();
    int wpre = 0;
    #pragma unroll
    for (int w = 0; w < 4; ++w) if (w < wid) wpre += wsum[w];
    if (t < NBLK) bsum[t] = s + wpre - v;
}

__global__ __launch_bounds__(256) void scan3_kernel(const int* __restrict__ part,
                                                    const int* __restrict__ bsum,
                                                    int* __restrict__ cursor,
                                                    int* __restrict__ rowptr) {
    int i = blockIdx.x * 256 + threadIdx.x;
    if (i < N_NODES) {
        int v = part[i] + bsum[blockIdx.x];
        cursor[i] = v;
        rowptr[i] = v;
    }
    if (blockIdx.x == 0 && threadIdx.x == 0) rowptr[N_NODES] = N_EDGES;
}

// combined scatter (round-4 proven version: ~105 us)
__global__ __launch_bounds__(256) void scatter_kernel(
    const int* __restrict__ src, const int* __restrict__ dst,
    const float* __restrict__ eattr, int* __restrict__ cursor,
    int* __restrict__ ssrc, int* __restrict__ sdst, float4* __restrict__ sea) {
    int e = blockIdx.x * 256 + threadIdx.x;
    if (e >= N_EDGES) return;
    int d = dst[e];
    int pos = atomicAdd(&cursor[d], 1);
    ssrc[pos] = src[e];
    sdst[pos] = d;
    sea[pos] = reinterpret_cast<const float4*>(eattr)[e];
}

// ---------- init: copy state + layer-0 per-node precompute ----------
__global__ __launch_bounds__(256) void init_kernel(
    const float* __restrict__ h0, const float* __restrict__ pos,
    float* __restrict__ h, float* __restrict__ x,
    const float* __restrict__ Wm1, const float* __restrict__ bm1,
    const float* __restrict__ Wx1, const float* __restrict__ bx1,
    float* __restrict__ preA, float* __restrict__ preB)
{
    __shared__ float sM[2 * F * F], sX[2 * F * F], sbm[F], sbx[F];
    int t = threadIdx.x;
    for (int i2 = t; i2 < 2 * F * F; i2 += 256) { sM[i2] = Wm1[i2]; sX[i2] = Wx1[i2]; }
    if (t < F) { sbm[t] = bm1[t]; sbx[t] = bx1[t]; }
    __syncthreads();

    int n = blockIdx.x * 256 + t;
    if (n >= N_NODES) return;

    float hv[F];
    #pragma unroll
    for (int f2 = 0; f2 < F; ++f2) { hv[f2] = h0[n * F + f2]; h[n * F + f2] = hv[f2]; }
    #pragma unroll
    for (int k = 0; k < 3; ++k) x[n * 3 + k] = pos[n * 3 + k];

    float am[F], bm_[F], ax[F], bx_[F];
    #pragma unroll
    for (int o = 0; o < F; ++o) { am[o] = sbm[o]; ax[o] = sbx[o]; bm_[o] = 0.f; bx_[o] = 0.f; }
    #pragma unroll
    for (int fi = 0; fi < F; ++fi) {
        float v = hv[fi];
        #pragma unroll
        for (int o = 0; o < F; ++o) {
            am[o]  = fmaf(v, sM[fi * F + o], am[o]);
            bm_[o] = fmaf(v, sM[(F + fi) * F + o], bm_[o]);
            ax[o]  = fmaf(v, sX[fi * F + o], ax[o]);
            bx_[o] = fmaf(v, sX[(F + fi) * F + o], bx_[o]);
        }
    }
    #pragma unroll
    for (int o = 0; o < F; ++o) {
        preA[n * PRESTRIDE + o]      = am[o];
        preA[n * PRESTRIDE + 12 + o] = ax[o];
        preB[n * PRESTRIDE + o]      = bm_[o];
        preB[n * PRESTRIDE + 12 + o] = bx_[o];
    }
    preA[n * PRESTRIDE + 11] = 0.f; preA[n * PRESTRIDE + 23] = 0.f;
    preB[n * PRESTRIDE + 11] = 0.f; preB[n * PRESTRIDE + 23] = 0.f;
}

// ---------- per-layer edge kernel: chunk-owned nodes, LDS agg, per-phase reduce ----------
__global__ __launch_bounds__(256) void edge_kernel(
    const float* __restrict__ preA, const float* __restrict__ preB,
    const float* __restrict__ x,
    const int* __restrict__ rowptr,
    const int* __restrict__ ssrc, const int* __restrict__ sdst,
    const float4* __restrict__ sea,
    const float* __restrict__ Wm1,                                  // rows 22..26
    const float* __restrict__ Wm2, const float* __restrict__ bm2,
    const float* __restrict__ Wa,  const float* __restrict__ ba,
    const float* __restrict__ Wx1,                                  // rows 22..26
    const float* __restrict__ Wx2, const float* __restrict__ bx2,
    const float* __restrict__ Wx3, const float* __restrict__ bx3,
    float* __restrict__ agg_h, float* __restrict__ agg_x)
{
    __shared__ float sWm2[F * F], sWx2[F * F];
    __shared__ float sMd2[F], sMea[4 * F], sXd2[F], sXea[4 * F];
    __shared__ float sbm2[F], sWa[F], sbx2[F], sWx3[F];
    __shared__ float sba, sbx3;
    __shared__ float sAgg[CHUNK_NODES][NVALS];
    __shared__ int sE[2];
    int t = threadIdx.x;
    for (int i2 = t; i2 < F * F; i2 += 256) { sWm2[i2] = Wm2[i2]; sWx2[i2] = Wx2[i2]; }
    if (t < F) {
        sMd2[t] = Wm1[22 * F + t]; sXd2[t] = Wx1[22 * F + t];
        sbm2[t] = bm2[t]; sWa[t] = Wa[t]; sbx2[t] = bx2[t]; sWx3[t] = Wx3[t];
    }
    if (t >= 64 && t < 64 + 4 * F) {
        int k = t - 64;
        sMea[k] = Wm1[23 * F + k];
        sXea[k] = Wx1[23 * F + k];
    }
    if (t == 0) { sba = ba[0]; sbx3 = bx3[0]; }
    for (int i2 = t; i2 < CHUNK_NODES * NVALS; i2 += 256) ((float*)sAgg)[i2] = 0.f;
    int nbase = blockIdx.x * CHUNK_NODES;
    if (t == 0) { sE[0] = rowptr[nbase]; sE[1] = rowptr[nbase + CHUNK_NODES]; }
    __syncthreads();

    int estart = sE[0], eend = sE[1];
    int K = (eend - estart + 255) >> 8;
    int lane = t & 63;

    for (int k = 0; k < K; ++k) {
        int e = estart + (k << 8) + t;
        bool act = (e < eend);
        int el = act ? e : (eend - 1);

        int j = ssrc[el];          // source (random)
        int d0 = sdst[el];         // target (sorted, chunk-local)
        int d = act ? d0 : -1;     // segment key (-1 = inactive)
        int slot = d0 - nbase;

        float xi0 = x[d0 * 3 + 0], xi1 = x[d0 * 3 + 1], xi2 = x[d0 * 3 + 2];
        float xj0 = x[j * 3 + 0],  xj1 = x[j * 3 + 1],  xj2 = x[j * 3 + 2];
        float dx = xj0 - xi0, dy = xj1 - xi1, dz = xj2 - xi2;
        float d2 = dx * dx + dy * dy + dz * dz;
        float4 ea = sea[el];

        int dprev = __shfl_up(d, 1);
        bool leader = (d >= 0) && (lane == 0 || dprev != d);

        // ---- phase 1: msg path -> reduce -> commit vals[0..11) ----
        {
            const float4* pa4 = reinterpret_cast<const float4*>(preA + (size_t)d0 * PRESTRIDE);
            const float4* pb4 = reinterpret_cast<const float4*>(preB + (size_t)j * PRESTRIDE);
            float4 a0 = pa4[0], a1 = pa4[1], a2 = pa4[2];
            float4 b0 = pb4[0], b1 = pb4[1], b2 = pb4[2];
            float pm[11];
            pm[0] = a0.x + b0.x; pm[1] = a0.y + b0.y; pm[2] = a0.z + b0.z; pm[3] = a0.w + b0.w;
            pm[4] = a1.x + b1.x; pm[5] = a1.y + b1.y; pm[6] = a1.z + b1.z; pm[7] = a1.w + b1.w;
            pm[8] = a2.x + b2.x; pm[9] = a2.y + b2.y; pm[10] = a2.z + b2.z;

            float tm[F];
            #pragma unroll
            for (int o = 0; o < F; ++o) {
                float v = pm[o];
                v = fmaf(d2,   sMd2[o],         v);
                v = fmaf(ea.x, sMea[0 * F + o], v);
                v = fmaf(ea.y, sMea[1 * F + o], v);
                v = fmaf(ea.z, sMea[2 * F + o], v);
                v = fmaf(ea.w, sMea[3 * F + o], v);
                tm[o] = siluf(v);
            }
            float m2[F];
            #pragma unroll
            for (int o = 0; o < F; ++o) m2[o] = sbm2[o];
            #pragma unroll
            for (int fi = 0; fi < F; ++fi) {
                float a = tm[fi];
                #pragma unroll
                for (int o = 0; o < F; ++o) m2[o] = fmaf(a, sWm2[fi * F + o], m2[o]);
            }
            float attn = sba;
            #pragma unroll
            for (int o = 0; o < F; ++o) { m2[o] = siluf(m2[o]); attn = fmaf(m2[o], sWa[o], attn); }
            attn = sigmf(attn);
            float vm[F];
            #pragma unroll
            for (int o = 0; o < F; ++o) vm[o] = attn * m2[o];

            #pragma unroll
            for (int off = 1; off < 64; off <<= 1) {
                int du = __shfl_down(d, off);
                bool ok = (lane + off < 64) && (du == d);
                #pragma unroll
                for (int kk = 0; kk < F; ++kk) {
                    float up = __shfl_down(vm[kk], off);
                    if (ok) vm[kk] += up;
                }
            }
            if (leader) {
                #pragma unroll
                for (int o = 0; o < F; ++o) atomicAdd(&sAgg[slot][o], vm[o]);
            }
        }

        __builtin_amdgcn_sched_barrier(0);

        // ---- phase 2: phi path -> reduce -> commit vals[11..14) ----
        {
            const float4* pa4 = reinterpret_cast<const float4*>(preA + (size_t)d0 * PRESTRIDE + 12);
            const float4* pb4 = reinterpret_cast<const float4*>(preB + (size_t)j * PRESTRIDE + 12);
            float4 a0 = pa4[0], a1 = pa4[1], a2 = pa4[2];
            float4 b0 = pb4[0], b1 = pb4[1], b2 = pb4[2];
            float px[11];
            px[0] = a0.x + b0.x; px[1] = a0.y + b0.y; px[2] = a0.z + b0.z; px[3] = a0.w + b0.w;
            px[4] = a1.x + b1.x; px[5] = a1.y + b1.y; px[6] = a1.z + b1.z; px[7] = a1.w + b1.w;
            px[8] = a2.x + b2.x; px[9] = a2.y + b2.y; px[10] = a2.z + b2.z;

            float tx[F];
            #pragma unroll
            for (int o = 0; o < F; ++o) {
                float v = px[o];
                v = fmaf(d2,   sXd2[o],         v);
                v = fmaf(ea.x, sXea[0 * F + o], v);
                v = fmaf(ea.y, sXea[1 * F + o], v);
                v = fmaf(ea.z, sXea[2 * F + o], v);
                v = fmaf(ea.w, sXea[3 * F + o], v);
                tx[o] = siluf(v);
            }
            float p2[F];
            #pragma unroll
            for (int o = 0; o < F; ++o) p2[o] = sbx2[o];
            #pragma unroll
            for (int fi = 0; fi < F; ++fi) {
                float a = tx[fi];
                #pragma unroll
                for (int o = 0; o < F; ++o) p2[o] = fmaf(a, sWx2[fi * F + o], p2[o]);
            }
            float phi = sbx3;
            #pragma unroll
            for (int o = 0; o < F; ++o) phi = fmaf(siluf(p2[o]), sWx3[o], phi);

            float dist = sqrtf(d2);
            float sc = phi / (dist + 1.0f);
            float vx[3];
            vx[0] = -dx * sc;   // (xi - xj) * sc
            vx[1] = -dy * sc;
            vx[2] = -dz * sc;

            #pragma unroll
            for (int off = 1; off < 64; off <<= 1) {
                int du = __shfl_down(d, off);
                bool ok = (lane + off < 64) && (du == d);
                #pragma unroll
                for (int kk = 0; kk < 3; ++kk) {
                    float up = __shfl_down(vx[kk], off);
                    if (ok) vx[kk] += up;
                }
            }
            if (leader) {
                #pragma unroll
                for (int o = 0; o < 3; ++o) atomicAdd(&sAgg[slot][F + o], vx[o]);
            }
        }
    }

    __syncthreads();
    for (int i2 = t; i2 < CHUNK_NODES * NVALS; i2 += 256) {
        int n = nbase + i2 / NVALS;
        int f = i2 % NVALS;
        float v = ((const float*)sAgg)[i2];
        if (f < F) agg_h[n * F + f] = v;
        else       agg_x[n * 3 + (f - F)] = v;
    }
}

// ---------- node update + fused precompute for next layer ----------
__global__ __launch_bounds__(256) void node_kernel(
    float* __restrict__ h, float* __restrict__ x,
    const float* __restrict__ agg_h, const float* __restrict__ agg_x,
    const float* __restrict__ Wu1, const float* __restrict__ bu1,
    const float* __restrict__ Wu2, const float* __restrict__ bu2,
    const float* __restrict__ Wm1n, const float* __restrict__ bm1n,
    const float* __restrict__ Wx1n, const float* __restrict__ bx1n,
    float* __restrict__ preA, float* __restrict__ preB, int has_next)
{
    __shared__ float sWu1[2 * F * F], sWu2[F * F], sbu1[F], sbu2[F];
    __shared__ float sM[2 * F * F], sX[2 * F * F], sbm[F], sbx[F];
    int t = threadIdx.x;
    for (int i2 = t; i2 < 2 * F * F; i2 += 256) sWu1[i2] = Wu1[i2];
    for (int i2 = t; i2 < F * F; i2 += 256)     sWu2[i2] = Wu2[i2];
    if (t < F) { sbu1[t] = bu1[t]; sbu2[t] = bu2[t]; }
    if (has_next) {
        for (int i2 = t; i2 < 2 * F * F; i2 += 256) { sM[i2] = Wm1n[i2]; sX[i2] = Wx1n[i2]; }
        if (t < F) { sbm[t] = bm1n[t]; sbx[t] = bx1n[t]; }
    }
    __syncthreads();

    int n = blockIdx.x * 256 + t;
    if (n >= N_NODES) return;

    float in[2 * F];
    #pragma unroll
    for (int f2 = 0; f2 < F; ++f2) in[f2] = h[n * F + f2];
    #pragma unroll
    for (int f2 = 0; f2 < F; ++f2) in[F + f2] = agg_h[n * F + f2];

    float u[F];
    #pragma unroll
    for (int o = 0; o < F; ++o) u[o] = sbu1[o];
    #pragma unroll
    for (int fi = 0; fi < 2 * F; ++fi) {
        float fv = in[fi];
        #pragma unroll
        for (int o = 0; o < F; ++o) u[o] = fmaf(fv, sWu1[fi * F + o], u[o]);
    }
    #pragma unroll
    for (int o = 0; o < F; ++o) u[o] = siluf(u[o]);

    float hn[F];
    #pragma unroll
    for (int o = 0; o < F; ++o) hn[o] = in[o] + sbu2[o];
    #pragma unroll
    for (int fi = 0; fi < F; ++fi) {
        float fv = u[fi];
        #pragma unroll
        for (int o = 0; o < F; ++o) hn[o] = fmaf(fv, sWu2[fi * F + o], hn[o]);
    }

    #pragma unroll
    for (int f2 = 0; f2 < F; ++f2) h[n * F + f2] = hn[f2];
    #pragma unroll
    for (int k = 0; k < 3; ++k) x[n * 3 + k] += agg_x[n * 3 + k];

    if (has_next) {
        float am[F], bm_[F], ax[F], bx_[F];
        #pragma unroll
        for (int o = 0; o < F; ++o) { am[o] = sbm[o]; ax[o] = sbx[o]; bm_[o] = 0.f; bx_[o] = 0.f; }
        #pragma unroll
        for (int fi = 0; fi < F; ++fi) {
            float v = hn[fi];
            #pragma unroll
            for (int o = 0; o < F; ++o) {
                am[o]  = fmaf(v, sM[fi * F + o], am[o]);
                bm_[o] = fmaf(v, sM[(F + fi) * F + o], bm_[o]);
                ax[o]  = fmaf(v, sX[fi * F + o], ax[o]);
                bx_[o] = fmaf(v, sX[(F + fi) * F + o], bx_[o]);
            }
        }
        #pragma unroll
        for (int o = 0; o < F; ++o) {
            preA[n * PRESTRIDE + o]      = am[o];
            preA[n * PRESTRIDE + 12 + o] = ax[o];
            preB[n * PRESTRIDE + o]      = bm_[o];
            preB[n * PRESTRIDE + 12 + o] = bx_[o];
        }
        preA[n * PRESTRIDE + 11] = 0.f; preA[n * PRESTRIDE + 23] = 0.f;
        preB[n * PRESTRIDE + 11] = 0.f; preB[n * PRESTRIDE + 23] = 0.f;
    }
}

// ---------- pool ----------
__global__ __launch_bounds__(256) void pool_kernel(
    const float* __restrict__ h, const int* __restrict__ batch,
    float* __restrict__ gsum, float* __restrict__ gcnt)
{
    int n = blockIdx.x * blockDim.x + threadIdx.x;
    int lane = threadIdx.x & 63;
    bool valid = (n < N_NODES);
    int g = valid ? batch[n] : -1;
    float vals[F + 1];
    #pragma unroll
    for (int f2 = 0; f2 < F; ++f2) vals[f2] = valid ? h[n * F + f2] : 0.0f;
    vals[F] = valid ? 1.0f : 0.0f;

    #pragma unroll
    for (int off = 1; off < 64; off <<= 1) {
        int gu = __shfl_down(g, off);
        bool ok = (lane + off < 64) && (gu == g);
        #pragma unroll
        for (int k = 0; k < F + 1; ++k) {
            float up = __shfl_down(vals[k], off);
            if (ok) vals[k] += up;
        }
    }
    int gprev = __shfl_up(g, 1);
    if (valid && (lane == 0 || gprev != g)) {
        #pragma unroll
        for (int f2 = 0; f2 < F; ++f2) unsafeAtomicAdd(&gsum[g * F + f2], vals[f2]);
        unsafeAtomicAdd(&gcnt[g], vals[F]);
    }
}

__global__ void head_kernel(const float* __restrict__ gsum, const float* __restrict__ gcnt,
                            const float* __restrict__ Wp, const float* __restrict__ bp,
                            float* __restrict__ out)
{
    int g = blockIdx.x * blockDim.x + threadIdx.x;
    if (g >= NGRAPH) return;
    float c = fmaxf(gcnt[g], 1.0f);
    float inv = 1.0f / c;
    float acc = bp[0];
    #pragma unroll
    for (int f2 = 0; f2 < F; ++f2) acc = fmaf(gsum[g * F + f2] * inv, Wp[f2], acc);
    out[g] = acc;
}

extern "C" void kernel_launch(void* const* d_in, const int* in_sizes, int n_in,
                              void* d_out, int out_size, void* d_ws, size_t ws_size,
                              hipStream_t stream)
{
    const float* h0    = (const float*)d_in[0];
    const float* pos   = (const float*)d_in[1];
    const int*   eidx  = (const int*)d_in[2];
    const float* eattr = (const float*)d_in[3];
    const int*   batch = (const int*)d_in[4];
    const float* Wm1 = (const float*)d_in[5];
    const float* bm1 = (const float*)d_in[6];
    const float* Wm2 = (const float*)d_in[7];
    const float* bm2 = (const float*)d_in[8];
    const float* Wa  = (const float*)d_in[9];
    const float* ba  = (const float*)d_in[10];
    const float* Wu1 = (const float*)d_in[11];
    const float* bu1 = (const float*)d_in[12];
    const float* Wu2 = (const float*)d_in[13];
    const float* bu2 = (const float*)d_in[14];
    const float* Wx1 = (const float*)d_in[15];
    const float* bx1 = (const float*)d_in[16];
    const float* Wx2 = (const float*)d_in[17];
    const float* bx2 = (const float*)d_in[18];
    const float* Wx3 = (const float*)d_in[19];
    const float* bx3 = (const float*)d_in[20];
    const float* Wp  = (const float*)d_in[21];
    const float* bp  = (const float*)d_in[22];

    char* base = (char*)d_ws;
    float4* sea  = (float4*)base;                         base += (size_t)N_EDGES * 16;
    float* preA  = (float*)base;                          base += (size_t)N_NODES * PRESTRIDE * 4;
    float* preB  = (float*)base;                          base += (size_t)N_NODES * PRESTRIDE * 4;
    float* h_cur = (float*)base;                          base += (size_t)N_NODES * F * 4;
    float* x_cur = (float*)base;                          base += (size_t)N_NODES * 3 * 4;
    float* agg_h = (float*)base;                          base += (size_t)N_NODES * F * 4;
    float* agg_x = (float*)base;                          base += (size_t)N_NODES * 3 * 4;
    float* gsum  = (float*)base;                          base += (size_t)NGRAPH * F * 4;
    float* gcnt  = (float*)base;                          base += (size_t)NGRAPH * 4;
    int*   deg   = (int*)base;                            base += (size_t)N_NODES * 4;
    int*   part  = (int*)base;                            base += (size_t)N_NODES * 4;
    int*   bsum  = (int*)base;                            base += (size_t)256 * 4;
    int*   cursor= (int*)base;                            base += (size_t)N_NODES * 4;
    int*   rowptr= (int*)base;                            base += (size_t)(N_NODES + 1) * 4;
    int*   ssrc  = (int*)base;                            base += (size_t)N_EDGES * 4;
    int*   sdst  = (int*)base;                            base += (size_t)N_EDGES * 4;

    const int* src = eidx;            // edge_index[0]
    const int* dst = eidx + N_EDGES;  // edge_index[1]

    // one-time: counting sort of edges by dst
    hipMemsetAsync(deg, 0, (size_t)N_NODES * sizeof(int), stream);
    hist_kernel<<<(N_EDGES + 255) / 256, 256, 0, stream>>>(dst, deg);
    scan1_kernel<<<NBLK, 256, 0, stream>>>(deg, part, bsum);
    scan2_kernel<<<1, 256, 0, stream>>>(bsum);
    scan3_kernel<<<NBLK, 256, 0, stream>>>(part, bsum, cursor, rowptr);
    scatter_kernel<<<(N_EDGES + 255) / 256, 256, 0, stream>>>(
        src, dst, eattr, cursor, ssrc, sdst, sea);

    init_kernel<<<NBLK, 256, 0, stream>>>(h0, pos, h_cur, x_cur,
                                          Wm1, bm1, Wx1, bx1, preA, preB);

    for (int l = 0; l < NLAYERS; ++l) {
        edge_kernel<<<NCHUNK, 256, 0, stream>>>(
            preA, preB, x_cur, rowptr, ssrc, sdst, sea,
            Wm1 + l * FEAT * F,
            Wm2 + l * F * F,    bm2 + l * F,
            Wa + l * F,         ba + l,
            Wx1 + l * FEAT * F,
            Wx2 + l * F * F,    bx2 + l * F,
            Wx3 + l * F,        bx3 + l,
            agg_h, agg_x);
        int nl = l + 1;
        int has_next = (nl < NLAYERS) ? 1 : 0;
        int wl = has_next ? nl : l;
        node_kernel<<<NBLK, 256, 0, stream>>>(
            h_cur, x_cur, agg_h, agg_x,
            Wu1 + l * 2 * F * F, bu1 + l * F,
            Wu2 + l * F * F,     bu2 + l * F,
            Wm1 + wl * FEAT * F, bm1 + wl * F,
            Wx1 + wl * FEAT * F, bx1 + wl * F,
            preA, preB, has_next);
    }

    hipMemsetAsync(gsum, 0, (size_t)(NGRAPH * F + NGRAPH) * sizeof(float), stream);
    pool_kernel<<<(N_NODES + 255) / 256, 256, 0, stream>>>(h_cur, batch, gsum, gcnt);
    head_kernel<<<2, 256, 0, stream>>>(gsum, gcnt, Wp, bp, (float*)d_out);
}